// Round 1
// baseline (6050.965 us; speedup 1.0000x reference)
//
#include <hip/hip_runtime.h>

#define HID 64

// ---- degree / normalization ----------------------------------------------
__global__ void k_init_deg(float* __restrict__ deg, int N) {
    int i = blockIdx.x * blockDim.x + threadIdx.x;
    if (i < N) deg[i] = 1.0f;  // self-loop included
}

__global__ void k_count(const int* __restrict__ col, float* __restrict__ deg, int E) {
    int e = blockIdx.x * blockDim.x + threadIdx.x;
    if (e < E) atomicAdd(&deg[col[e]], 1.0f);  // integer-valued fp adds: exact, deterministic
}

__global__ void k_rsqrt_inplace(float* __restrict__ d, int N) {
    int i = blockIdx.x * blockDim.x + threadIdx.x;
    if (i < N) d[i] = rsqrtf(d[i]);
}

// ---- layer 1: g1 = dinv * (x @ W1); agg init = g1 (self loop) ------------
__global__ void k_lin1(const float* __restrict__ x, const float* __restrict__ W1,
                       const float* __restrict__ dinv,
                       float* __restrict__ g, float* __restrict__ agg, int N) {
    int idx = blockIdx.x * blockDim.x + threadIdx.x;
    int n = idx >> 6, f = idx & 63;
    if (n >= N) return;
    float x0 = x[n * 3 + 0], x1 = x[n * 3 + 1], x2 = x[n * 3 + 2];
    float acc = x0 * W1[f] + x1 * W1[64 + f] + x2 * W1[128 + f];
    float val = dinv[n] * acc;
    g[idx] = val;
    agg[idx] = val;
}

// ---- scatter: agg[col] += g[row], 16 lanes per edge, float4 chunks -------
__global__ void k_scatter(const float4* __restrict__ g4, const int* __restrict__ row,
                          const int* __restrict__ col, float* __restrict__ agg, int E) {
    int idx = blockIdx.x * blockDim.x + threadIdx.x;
    int e = idx >> 4, c = idx & 15;
    if (e >= E) return;
    int r = row[e], t = col[e];
    float4 v = g4[r * 16 + c];
    float* dst = agg + (size_t)t * 64 + c * 4;
    atomicAdd(dst + 0, v.x);
    atomicAdd(dst + 1, v.y);
    atomicAdd(dst + 2, v.z);
    atomicAdd(dst + 3, v.w);
}

// ---- post: h = relu(dinv * agg + b) --------------------------------------
__global__ void k_post(const float* __restrict__ agg, const float* __restrict__ dinv,
                       const float* __restrict__ b, float* __restrict__ h, int N) {
    int idx = blockIdx.x * blockDim.x + threadIdx.x;
    int n = idx >> 6, f = idx & 63;
    if (n >= N) return;
    float v = fmaf(dinv[n], agg[idx], b[f]);
    h[idx] = fmaxf(v, 0.0f);
}

// ---- 64x64 GEMM, wave per node: g = dinv * (h @ W) -----------------------
__global__ void k_lin64(const float* __restrict__ h, const float* __restrict__ W,
                        const float* __restrict__ dinv,
                        float* __restrict__ g, float* __restrict__ agg, int N) {
    __shared__ float Wl[64 * 64];
    int tid = threadIdx.x;
    for (int i = tid; i < 4096; i += 256) Wl[i] = W[i];
    __syncthreads();
    int wave = tid >> 6, lane = tid & 63;
    int n = blockIdx.x * 4 + wave;
    if (n >= N) return;
    float hv = h[n * 64 + lane];
    float acc = 0.f;
#pragma unroll
    for (int k = 0; k < 64; k++) {
        float hk = __shfl(hv, k);
        acc = fmaf(hk, Wl[k * 64 + lane], acc);
    }
    float val = dinv[n] * acc;
    g[n * 64 + lane] = val;
    agg[n * 64 + lane] = val;
}

// ---- edge-MLP node precompute: u = h@W3a + b3, v = h@W3b -----------------
__global__ void k_lin3(const float* __restrict__ h, const float* __restrict__ W3,
                       const float* __restrict__ b3,
                       float* __restrict__ u, float* __restrict__ v, int N) {
    __shared__ float Wa[4096];
    __shared__ float Wb[4096];
    int tid = threadIdx.x;
    for (int i = tid; i < 4096; i += 256) {
        Wa[i] = W3[i];
        Wb[i] = W3[4096 + i];
    }
    __syncthreads();
    int wave = tid >> 6, lane = tid & 63;
    int n = blockIdx.x * 4 + wave;
    if (n >= N) return;
    float hv = h[n * 64 + lane];
    float ua = b3[lane], va = 0.f;
#pragma unroll
    for (int k = 0; k < 64; k++) {
        float hk = __shfl(hv, k);
        ua = fmaf(hk, Wa[k * 64 + lane], ua);
        va = fmaf(hk, Wb[k * 64 + lane], va);
    }
    u[n * 64 + lane] = ua;
    v[n * 64 + lane] = va;
}

// ---- final: out[e] = relu(u[row]+v[col]) @ W4 + b4 -----------------------
__global__ void k_edge(const float4* __restrict__ u4, const float4* __restrict__ v4,
                       const int* __restrict__ row, const int* __restrict__ col,
                       const float4* __restrict__ w44, const float* __restrict__ b4,
                       float* __restrict__ out, int E) {
    int idx = blockIdx.x * blockDim.x + threadIdx.x;
    int e = idx >> 4, c = idx & 15;
    if (e >= E) return;
    int r = row[e], t = col[e];
    float4 a = u4[r * 16 + c];
    float4 b = v4[t * 16 + c];
    float4 w = w44[c];
    float s = fmaxf(a.x + b.x, 0.f) * w.x + fmaxf(a.y + b.y, 0.f) * w.y +
              fmaxf(a.z + b.z, 0.f) * w.z + fmaxf(a.w + b.w, 0.f) * w.w;
    s += __shfl_xor(s, 1);
    s += __shfl_xor(s, 2);
    s += __shfl_xor(s, 4);
    s += __shfl_xor(s, 8);
    if (c == 0) out[e] = s + b4[0];
}

extern "C" void kernel_launch(void* const* d_in, const int* in_sizes, int n_in,
                              void* d_out, int out_size, void* d_ws, size_t ws_size,
                              hipStream_t stream) {
    const float* x  = (const float*)d_in[0];
    const int*   ei = (const int*)d_in[1];
    const float* W1 = (const float*)d_in[2];
    const float* b1 = (const float*)d_in[3];
    const float* W2 = (const float*)d_in[4];
    const float* b2 = (const float*)d_in[5];
    const float* W3 = (const float*)d_in[6];
    const float* b3 = (const float*)d_in[7];
    const float* W4 = (const float*)d_in[8];
    const float* b4 = (const float*)d_in[9];
    int N = in_sizes[0] / 3;
    int E = in_sizes[1] / 2;
    const int* row = ei;
    const int* col = ei + E;
    float* out = (float*)d_out;

    char* ws = (char*)d_ws;
    size_t off = 0;
    auto alloc = [&](size_t bytes) {
        void* p = ws + off;
        off += (bytes + 255) & ~(size_t)255;
        return p;
    };
    float* dinv = (float*)alloc((size_t)N * 4);
    float* bufA = (float*)alloc((size_t)N * 64 * 4);
    float* bufB = (float*)alloc((size_t)N * 64 * 4);
    float* bufC = (float*)alloc((size_t)N * 64 * 4);

    dim3 B(256);
    int nbN     = (N + 255) / 256;
    int nbNF    = (N * 64 + 255) / 256;
    int nbE     = (E + 255) / 256;
    int nbE16   = (int)(((long long)E * 16 + 255) / 256);
    int nbNode4 = (N + 3) / 4;

    // normalization
    k_init_deg<<<nbN, B, 0, stream>>>(dinv, N);
    k_count<<<nbE, B, 0, stream>>>(col, dinv, E);
    k_rsqrt_inplace<<<nbN, B, 0, stream>>>(dinv, N);
    // layer 1: g1=bufA, agg1=bufB -> h1=bufC
    k_lin1<<<nbNF, B, 0, stream>>>(x, W1, dinv, bufA, bufB, N);
    k_scatter<<<nbE16, B, 0, stream>>>((const float4*)bufA, row, col, bufB, E);
    k_post<<<nbNF, B, 0, stream>>>(bufB, dinv, b1, bufC, N);
    // layer 2: g2=bufA, agg2=bufB -> h2=bufC
    k_lin64<<<nbNode4, B, 0, stream>>>(bufC, W2, dinv, bufA, bufB, N);
    k_scatter<<<nbE16, B, 0, stream>>>((const float4*)bufA, row, col, bufB, E);
    k_post<<<nbNF, B, 0, stream>>>(bufB, dinv, b2, bufC, N);
    // edge MLP: u=bufA, v=bufB
    k_lin3<<<nbNode4, B, 0, stream>>>(bufC, W3, b3, bufA, bufB, N);
    k_edge<<<nbE16, B, 0, stream>>>((const float4*)bufA, (const float4*)bufB, row, col,
                                    (const float4*)W4, b4, out, E);
}

// Round 2
// 1204.828 us; speedup vs baseline: 5.0223x; 5.0223x over previous
//
#include <hip/hip_runtime.h>

// ---- CSR build -----------------------------------------------------------
__global__ void k_zero_i(int* __restrict__ p, int N) {
    int i = blockIdx.x * blockDim.x + threadIdx.x;
    if (i < N) p[i] = 0;
}

__global__ void k_hist(const int* __restrict__ col, int* __restrict__ deg, int E) {
    int e = blockIdx.x * blockDim.x + threadIdx.x;
    if (e < E) atomicAdd(&deg[col[e]], 1);
}

__global__ void k_dinv(const int* __restrict__ deg, float* __restrict__ dinv, int N) {
    int i = blockIdx.x * blockDim.x + threadIdx.x;
    if (i < N) dinv[i] = rsqrtf((float)deg[i] + 1.0f);  // +1 self loop
}

// block-level exclusive scan (256 elems / block)
__global__ void k_scan1(const int* __restrict__ deg, int* __restrict__ part,
                        int* __restrict__ bsum, int N) {
    __shared__ int sm[256];
    int t = threadIdx.x;
    int i = blockIdx.x * 256 + t;
    int v = (i < N) ? deg[i] : 0;
    sm[t] = v;
    __syncthreads();
    for (int d = 1; d < 256; d <<= 1) {
        int add = (t >= d) ? sm[t - d] : 0;
        __syncthreads();
        sm[t] += add;
        __syncthreads();
    }
    if (i < N) part[i] = sm[t] - v;  // exclusive
    if (t == 255) bsum[blockIdx.x] = sm[255];
}

__global__ void k_scan2(int* __restrict__ bsum, int nb) {
    __shared__ int sm[512];
    int t = threadIdx.x;
    int v = (t < nb) ? bsum[t] : 0;
    sm[t] = v;
    __syncthreads();
    for (int d = 1; d < 512; d <<= 1) {
        int add = (t >= d) ? sm[t - d] : 0;
        __syncthreads();
        sm[t] += add;
        __syncthreads();
    }
    if (t < nb) bsum[t] = sm[t] - v;  // exclusive block offsets
}

__global__ void k_scan3(const int* __restrict__ part, const int* __restrict__ bsum,
                        int* __restrict__ off, int* __restrict__ cursor, int N, int E) {
    int i = blockIdx.x * 256 + threadIdx.x;
    if (i < N) {
        int o = part[i] + bsum[blockIdx.x];
        off[i] = o;
        cursor[i] = o;
    }
    if (i == 0) off[N] = E;
}

__global__ void k_fill(const int* __restrict__ row, const int* __restrict__ col,
                       int* __restrict__ cursor, int* __restrict__ rowlist, int E) {
    int e = blockIdx.x * blockDim.x + threadIdx.x;
    if (e < E) {
        int p = atomicAdd(&cursor[col[e]], 1);
        rowlist[p] = row[e];
    }
}

// ---- layer 1: g1 = dinv * (x @ W1) ---------------------------------------
__global__ void k_lin1(const float* __restrict__ x, const float* __restrict__ W1,
                       const float* __restrict__ dinv, float* __restrict__ g, int N) {
    int idx = blockIdx.x * blockDim.x + threadIdx.x;
    int n = idx >> 6, f = idx & 63;
    if (n >= N) return;
    float x0 = x[n * 3 + 0], x1 = x[n * 3 + 1], x2 = x[n * 3 + 2];
    float acc = x0 * W1[f] + x1 * W1[64 + f] + x2 * W1[128 + f];
    g[idx] = dinv[n] * acc;
}

// ---- gather-aggregate: h[n] = relu(dinv[n]*(g[n] + sum_in g[r]) + b) -----
__global__ void k_gather(const float* __restrict__ g, const int* __restrict__ off,
                         const int* __restrict__ rowlist, const float* __restrict__ dinv,
                         const float* __restrict__ b, float* __restrict__ h, int N) {
    int tid = threadIdx.x;
    int wave = tid >> 6, lane = tid & 63;
    int n = blockIdx.x * 4 + wave;
    if (n >= N) return;
    int s = off[n], epos = off[n + 1];
    float acc = g[(size_t)n * 64 + lane];  // self loop
    float acc2 = 0.f;
    int j = s;
    for (; j + 1 < epos; j += 2) {
        int r0 = rowlist[j], r1 = rowlist[j + 1];
        acc += g[(size_t)r0 * 64 + lane];
        acc2 += g[(size_t)r1 * 64 + lane];
    }
    if (j < epos) acc += g[(size_t)rowlist[j] * 64 + lane];
    acc += acc2;
    h[(size_t)n * 64 + lane] = fmaxf(fmaf(dinv[n], acc, b[lane]), 0.0f);
}

// ---- 64x64 GEMM, wave per node: g = dinv * (h @ W) -----------------------
__global__ void k_lin64(const float* __restrict__ h, const float* __restrict__ W,
                        const float* __restrict__ dinv, float* __restrict__ g, int N) {
    __shared__ float Wl[64 * 64];
    int tid = threadIdx.x;
    for (int i = tid; i < 4096; i += 256) Wl[i] = W[i];
    __syncthreads();
    int wave = tid >> 6, lane = tid & 63;
    int n = blockIdx.x * 4 + wave;
    if (n >= N) return;
    float hv = h[(size_t)n * 64 + lane];
    float acc = 0.f;
#pragma unroll
    for (int k = 0; k < 64; k++) {
        float hk = __shfl(hv, k);
        acc = fmaf(hk, Wl[k * 64 + lane], acc);
    }
    g[(size_t)n * 64 + lane] = dinv[n] * acc;
}

// ---- edge-MLP node precompute: u = h@W3a + b3, v = h@W3b -----------------
__global__ void k_lin3(const float* __restrict__ h, const float* __restrict__ W3,
                       const float* __restrict__ b3,
                       float* __restrict__ u, float* __restrict__ v, int N) {
    __shared__ float Wa[4096];
    __shared__ float Wb[4096];
    int tid = threadIdx.x;
    for (int i = tid; i < 4096; i += 256) {
        Wa[i] = W3[i];
        Wb[i] = W3[4096 + i];
    }
    __syncthreads();
    int wave = tid >> 6, lane = tid & 63;
    int n = blockIdx.x * 4 + wave;
    if (n >= N) return;
    float hv = h[(size_t)n * 64 + lane];
    float ua = b3[lane], va = 0.f;
#pragma unroll
    for (int k = 0; k < 64; k++) {
        float hk = __shfl(hv, k);
        ua = fmaf(hk, Wa[k * 64 + lane], ua);
        va = fmaf(hk, Wb[k * 64 + lane], va);
    }
    u[(size_t)n * 64 + lane] = ua;
    v[(size_t)n * 64 + lane] = va;
}

// ---- final: out[e] = relu(u[row]+v[col]) @ W4 + b4 -----------------------
__global__ void k_edge(const float4* __restrict__ u4, const float4* __restrict__ v4,
                       const int* __restrict__ row, const int* __restrict__ col,
                       const float4* __restrict__ w44, const float* __restrict__ b4,
                       float* __restrict__ out, int E) {
    int idx = blockIdx.x * blockDim.x + threadIdx.x;
    int e = idx >> 4, c = idx & 15;
    if (e >= E) return;
    int r = row[e], t = col[e];
    float4 a = u4[(size_t)r * 16 + c];
    float4 b = v4[(size_t)t * 16 + c];
    float4 w = w44[c];
    float s = fmaxf(a.x + b.x, 0.f) * w.x + fmaxf(a.y + b.y, 0.f) * w.y +
              fmaxf(a.z + b.z, 0.f) * w.z + fmaxf(a.w + b.w, 0.f) * w.w;
    s += __shfl_xor(s, 1);
    s += __shfl_xor(s, 2);
    s += __shfl_xor(s, 4);
    s += __shfl_xor(s, 8);
    if (c == 0) out[e] = s + b4[0];
}

extern "C" void kernel_launch(void* const* d_in, const int* in_sizes, int n_in,
                              void* d_out, int out_size, void* d_ws, size_t ws_size,
                              hipStream_t stream) {
    const float* x  = (const float*)d_in[0];
    const int*   ei = (const int*)d_in[1];
    const float* W1 = (const float*)d_in[2];
    const float* b1 = (const float*)d_in[3];
    const float* W2 = (const float*)d_in[4];
    const float* b2 = (const float*)d_in[5];
    const float* W3 = (const float*)d_in[6];
    const float* b3 = (const float*)d_in[7];
    const float* W4 = (const float*)d_in[8];
    const float* b4 = (const float*)d_in[9];
    int N = in_sizes[0] / 3;
    int E = in_sizes[1] / 2;
    const int* row = ei;
    const int* col = ei + E;
    float* out = (float*)d_out;

    char* ws = (char*)d_ws;
    size_t off_b = 0;
    auto alloc = [&](size_t bytes) {
        void* p = ws + off_b;
        off_b += (bytes + 255) & ~(size_t)255;
        return p;
    };
    float* dinv   = (float*)alloc((size_t)N * 4);
    int*   offs   = (int*)alloc((size_t)(N + 1) * 4);
    int*   bsum   = (int*)alloc(512 * 4);
    float* bufA   = (float*)alloc((size_t)N * 64 * 4);
    float* bufB   = (float*)alloc((size_t)N * 64 * 4);
    float* bufC   = (float*)alloc((size_t)N * 64 * 4);
    // aliases into regions that are only written later:
    int* part    = (int*)bufA;            // dead before lin1 writes bufA
    int* deg     = (int*)bufB;            // dead before gather1 writes bufB
    int* cursor  = (int*)bufB + N;        // dead before gather1 writes bufB
    int* rowlist = (int*)bufC;            // dead before lin3 writes bufC

    dim3 B(256);
    int nbN     = (N + 255) / 256;
    int nbNF    = (N * 64 + 255) / 256;
    int nbE     = (E + 255) / 256;
    int nbE16   = (int)(((long long)E * 16 + 255) / 256);
    int nbNode4 = (N + 3) / 4;

    // --- CSR build + normalization ---
    k_zero_i<<<nbN, B, 0, stream>>>(deg, N);
    k_hist<<<nbE, B, 0, stream>>>(col, deg, E);
    k_scan1<<<nbN, B, 0, stream>>>(deg, part, bsum, N);
    k_scan2<<<1, 512, 0, stream>>>(bsum, nbN);
    k_dinv<<<nbN, B, 0, stream>>>(deg, dinv, N);
    k_scan3<<<nbN, B, 0, stream>>>(part, bsum, offs, cursor, N, E);
    k_fill<<<nbE, B, 0, stream>>>(row, col, cursor, rowlist, E);

    // --- layer 1: g1=bufA -> h1=bufB ---
    k_lin1<<<nbNF, B, 0, stream>>>(x, W1, dinv, bufA, N);
    k_gather<<<nbNode4, B, 0, stream>>>(bufA, offs, rowlist, dinv, b1, bufB, N);
    // --- layer 2: g2=bufA -> h2=bufB ---
    k_lin64<<<nbNode4, B, 0, stream>>>(bufB, W2, dinv, bufA, N);
    k_gather<<<nbNode4, B, 0, stream>>>(bufA, offs, rowlist, dinv, b2, bufB, N);
    // --- edge MLP: u=bufA, v=bufC ---
    k_lin3<<<nbNode4, B, 0, stream>>>(bufB, W3, b3, bufA, bufC, N);
    k_edge<<<nbE16, B, 0, stream>>>((const float4*)bufA, (const float4*)bufC, row, col,
                                    (const float4*)W4, b4, out, E);
}

// Round 3
// 969.058 us; speedup vs baseline: 6.2442x; 1.2433x over previous
//
#include <hip/hip_runtime.h>

// ---- CSR build -----------------------------------------------------------
__global__ void k_zero_i(int* __restrict__ p, int N) {
    int i = blockIdx.x * blockDim.x + threadIdx.x;
    if (i < N) p[i] = 0;
}

__global__ void k_hist(const int* __restrict__ col, int* __restrict__ deg, int E) {
    int e = blockIdx.x * blockDim.x + threadIdx.x;
    if (e < E) atomicAdd(&deg[col[e]], 1);
}

__global__ void k_dinv(const int* __restrict__ deg, float* __restrict__ dinv, int N) {
    int i = blockIdx.x * blockDim.x + threadIdx.x;
    if (i < N) dinv[i] = rsqrtf((float)deg[i] + 1.0f);  // +1 self loop
}

// block-level exclusive scan (256 elems / block)
__global__ void k_scan1(const int* __restrict__ deg, int* __restrict__ part,
                        int* __restrict__ bsum, int N) {
    __shared__ int sm[256];
    int t = threadIdx.x;
    int i = blockIdx.x * 256 + t;
    int v = (i < N) ? deg[i] : 0;
    sm[t] = v;
    __syncthreads();
    for (int d = 1; d < 256; d <<= 1) {
        int add = (t >= d) ? sm[t - d] : 0;
        __syncthreads();
        sm[t] += add;
        __syncthreads();
    }
    if (i < N) part[i] = sm[t] - v;  // exclusive
    if (t == 255) bsum[blockIdx.x] = sm[255];
}

__global__ void k_scan2(int* __restrict__ bsum, int nb) {
    __shared__ int sm[512];
    int t = threadIdx.x;
    int v = (t < nb) ? bsum[t] : 0;
    sm[t] = v;
    __syncthreads();
    for (int d = 1; d < 512; d <<= 1) {
        int add = (t >= d) ? sm[t - d] : 0;
        __syncthreads();
        sm[t] += add;
        __syncthreads();
    }
    if (t < nb) bsum[t] = sm[t] - v;  // exclusive block offsets
}

__global__ void k_scan3(const int* __restrict__ part, const int* __restrict__ bsum,
                        int* __restrict__ off, int* __restrict__ cursor, int N, int E) {
    int i = blockIdx.x * 256 + threadIdx.x;
    if (i < N) {
        int o = part[i] + bsum[blockIdx.x];
        off[i] = o;
        cursor[i] = o;
    }
    if (i == 0) off[N] = E;
}

// XCD-partitioned fill: blocks round-robin across the 8 XCDs by blockIdx%8,
// block handles only cols in its node range -> rowlist writes for range r
// come only from XCD r and span a ~1.6MB region that fits its 4MB L2, so
// 64B lines fully populate before writeback (fixes 15x write amplification).
__global__ void k_fill_part(const int* __restrict__ row, const int* __restrict__ col,
                            int* __restrict__ cursor, int* __restrict__ rowlist,
                            int E, int N) {
    int r = blockIdx.x & 7;         // node-range id == (assumed) XCD id
    int chunk = blockIdx.x >> 3;
    int nchunks = gridDim.x >> 3;
    int lo = (int)((long long)N * r >> 3);
    int hi = (int)((long long)N * (r + 1) >> 3);
    long long c0 = (long long)E * chunk / nchunks;
    long long c1 = (long long)E * (chunk + 1) / nchunks;
    for (long long e = c0 + threadIdx.x; e < c1; e += blockDim.x) {
        int c = col[e];
        if (c >= lo && c < hi) {
            int p = atomicAdd(&cursor[c], 1);
            rowlist[p] = row[e];
        }
    }
}

// ---- layer 1: g1 = dinv * (x @ W1) ---------------------------------------
__global__ void k_lin1(const float* __restrict__ x, const float* __restrict__ W1,
                       const float* __restrict__ dinv, float* __restrict__ g, int N) {
    int idx = blockIdx.x * blockDim.x + threadIdx.x;
    int n = idx >> 6, f = idx & 63;
    if (n >= N) return;
    float x0 = x[n * 3 + 0], x1 = x[n * 3 + 1], x2 = x[n * 3 + 2];
    float acc = x0 * W1[f] + x1 * W1[64 + f] + x2 * W1[128 + f];
    g[idx] = dinv[n] * acc;
}

// ---- gather-aggregate: h[n] = relu(dinv[n]*(g[n] + sum_in g[r]) + b) -----
__global__ void k_gather(const float* __restrict__ g, const int* __restrict__ off,
                         const int* __restrict__ rowlist, const float* __restrict__ dinv,
                         const float* __restrict__ b, float* __restrict__ h, int N) {
    int tid = threadIdx.x;
    int wave = tid >> 6, lane = tid & 63;
    int n = blockIdx.x * 4 + wave;
    if (n >= N) return;
    int s = off[n], epos = off[n + 1];
    float a0 = g[(size_t)n * 64 + lane];  // self loop
    float a1 = 0.f, a2 = 0.f, a3 = 0.f;
    int j = s;
    for (; j + 3 < epos; j += 4) {
        int r0 = rowlist[j], r1 = rowlist[j + 1], r2 = rowlist[j + 2], r3 = rowlist[j + 3];
        a0 += g[(size_t)r0 * 64 + lane];
        a1 += g[(size_t)r1 * 64 + lane];
        a2 += g[(size_t)r2 * 64 + lane];
        a3 += g[(size_t)r3 * 64 + lane];
    }
    for (; j < epos; j++) a1 += g[(size_t)rowlist[j] * 64 + lane];
    float acc = (a0 + a1) + (a2 + a3);
    h[(size_t)n * 64 + lane] = fmaxf(fmaf(dinv[n], acc, b[lane]), 0.0f);
}

// ---- 64x64 GEMM, wave per node: g = dinv * (h @ W) -----------------------
__global__ void k_lin64(const float* __restrict__ h, const float* __restrict__ W,
                        const float* __restrict__ dinv, float* __restrict__ g, int N) {
    __shared__ float Wl[64 * 64];
    int tid = threadIdx.x;
    for (int i = tid; i < 4096; i += 256) Wl[i] = W[i];
    __syncthreads();
    int wave = tid >> 6, lane = tid & 63;
    int n = blockIdx.x * 4 + wave;
    if (n >= N) return;
    float hv = h[(size_t)n * 64 + lane];
    float acc = 0.f;
#pragma unroll
    for (int k = 0; k < 64; k++) {
        float hk = __shfl(hv, k);
        acc = fmaf(hk, Wl[k * 64 + lane], acc);
    }
    g[(size_t)n * 64 + lane] = dinv[n] * acc;
}

// ---- edge-MLP node precompute: u = h@W3a + b3, v = h@W3b -----------------
__global__ void k_lin3(const float* __restrict__ h, const float* __restrict__ W3,
                       const float* __restrict__ b3,
                       float* __restrict__ u, float* __restrict__ v, int N) {
    __shared__ float Wa[4096];
    __shared__ float Wb[4096];
    int tid = threadIdx.x;
    for (int i = tid; i < 4096; i += 256) {
        Wa[i] = W3[i];
        Wb[i] = W3[4096 + i];
    }
    __syncthreads();
    int wave = tid >> 6, lane = tid & 63;
    int n = blockIdx.x * 4 + wave;
    if (n >= N) return;
    float hv = h[(size_t)n * 64 + lane];
    float ua = b3[lane], va = 0.f;
#pragma unroll
    for (int k = 0; k < 64; k++) {
        float hk = __shfl(hv, k);
        ua = fmaf(hk, Wa[k * 64 + lane], ua);
        va = fmaf(hk, Wb[k * 64 + lane], va);
    }
    u[(size_t)n * 64 + lane] = ua;
    v[(size_t)n * 64 + lane] = va;
}

// ---- final: out[e] = relu(u[row]+v[col]) @ W4 + b4 -----------------------
__global__ void k_edge(const float4* __restrict__ u4, const float4* __restrict__ v4,
                       const int* __restrict__ row, const int* __restrict__ col,
                       const float4* __restrict__ w44, const float* __restrict__ b4,
                       float* __restrict__ out, int E) {
    int idx = blockIdx.x * blockDim.x + threadIdx.x;
    int e = idx >> 4, c = idx & 15;
    if (e >= E) return;
    int r = row[e], t = col[e];
    float4 a = u4[(size_t)r * 16 + c];
    float4 b = v4[(size_t)t * 16 + c];
    float4 w = w44[c];
    float s = fmaxf(a.x + b.x, 0.f) * w.x + fmaxf(a.y + b.y, 0.f) * w.y +
              fmaxf(a.z + b.z, 0.f) * w.z + fmaxf(a.w + b.w, 0.f) * w.w;
    s += __shfl_xor(s, 1);
    s += __shfl_xor(s, 2);
    s += __shfl_xor(s, 4);
    s += __shfl_xor(s, 8);
    if (c == 0) out[e] = s + b4[0];
}

extern "C" void kernel_launch(void* const* d_in, const int* in_sizes, int n_in,
                              void* d_out, int out_size, void* d_ws, size_t ws_size,
                              hipStream_t stream) {
    const float* x  = (const float*)d_in[0];
    const int*   ei = (const int*)d_in[1];
    const float* W1 = (const float*)d_in[2];
    const float* b1 = (const float*)d_in[3];
    const float* W2 = (const float*)d_in[4];
    const float* b2 = (const float*)d_in[5];
    const float* W3 = (const float*)d_in[6];
    const float* b3 = (const float*)d_in[7];
    const float* W4 = (const float*)d_in[8];
    const float* b4 = (const float*)d_in[9];
    int N = in_sizes[0] / 3;
    int E = in_sizes[1] / 2;
    const int* row = ei;
    const int* col = ei + E;
    float* out = (float*)d_out;

    char* ws = (char*)d_ws;
    size_t off_b = 0;
    auto alloc = [&](size_t bytes) {
        void* p = ws + off_b;
        off_b += (bytes + 255) & ~(size_t)255;
        return p;
    };
    float* dinv   = (float*)alloc((size_t)N * 4);
    int*   offs   = (int*)alloc((size_t)(N + 1) * 4);
    int*   bsum   = (int*)alloc(512 * 4);
    float* bufA   = (float*)alloc((size_t)N * 64 * 4);
    float* bufB   = (float*)alloc((size_t)N * 64 * 4);
    float* bufC   = (float*)alloc((size_t)N * 64 * 4);
    // aliases into regions that are only written later:
    int* part    = (int*)bufA;            // dead before lin1 writes bufA
    int* deg     = (int*)bufB;            // dead before gather1 writes bufB
    int* cursor  = (int*)bufB + N;        // dead before gather1 writes bufB
    int* rowlist = (int*)bufC;            // dead before lin3 writes bufC

    dim3 B(256);
    int nbN     = (N + 255) / 256;
    int nbNF    = (N * 64 + 255) / 256;
    int nbE     = (E + 255) / 256;
    int nbE16   = (int)(((long long)E * 16 + 255) / 256);
    int nbNode4 = (N + 3) / 4;

    // --- CSR build + normalization ---
    k_zero_i<<<nbN, B, 0, stream>>>(deg, N);
    k_hist<<<nbE, B, 0, stream>>>(col, deg, E);
    k_scan1<<<nbN, B, 0, stream>>>(deg, part, bsum, N);
    k_scan2<<<1, 512, 0, stream>>>(bsum, nbN);
    k_dinv<<<nbN, B, 0, stream>>>(deg, dinv, N);
    k_scan3<<<nbN, B, 0, stream>>>(part, bsum, offs, cursor, N, E);
    k_fill_part<<<2048, B, 0, stream>>>(row, col, cursor, rowlist, E, N);

    // --- layer 1: g1=bufA -> h1=bufB ---
    k_lin1<<<nbNF, B, 0, stream>>>(x, W1, dinv, bufA, N);
    k_gather<<<nbNode4, B, 0, stream>>>(bufA, offs, rowlist, dinv, b1, bufB, N);
    // --- layer 2: g2=bufA -> h2=bufB ---
    k_lin64<<<nbNode4, B, 0, stream>>>(bufB, W2, dinv, bufA, N);
    k_gather<<<nbNode4, B, 0, stream>>>(bufA, offs, rowlist, dinv, b2, bufB, N);
    // --- edge MLP: u=bufA, v=bufC ---
    k_lin3<<<nbNode4, B, 0, stream>>>(bufB, W3, b3, bufA, bufC, N);
    k_edge<<<nbE16, B, 0, stream>>>((const float4*)bufA, (const float4*)bufC, row, col,
                                    (const float4*)W4, b4, out, E);
}

// Round 4
// 905.936 us; speedup vs baseline: 6.6792x; 1.0697x over previous
//
#include <hip/hip_runtime.h>

// ---- CSR build -----------------------------------------------------------
__global__ void k_zero_i(int* __restrict__ p, int N) {
    int i = blockIdx.x * blockDim.x + threadIdx.x;
    if (i < N) p[i] = 0;
}

__global__ void k_hist(const int* __restrict__ col, int* __restrict__ deg, int E) {
    int e = blockIdx.x * blockDim.x + threadIdx.x;
    if (e < E) atomicAdd(&deg[col[e]], 1);
}

__global__ void k_dinv(const int* __restrict__ deg, float* __restrict__ dinv, int N) {
    int i = blockIdx.x * blockDim.x + threadIdx.x;
    if (i < N) dinv[i] = rsqrtf((float)deg[i] + 1.0f);  // +1 self loop
}

// block-level exclusive scan (256 elems / block)
__global__ void k_scan1(const int* __restrict__ deg, int* __restrict__ part,
                        int* __restrict__ bsum, int N) {
    __shared__ int sm[256];
    int t = threadIdx.x;
    int i = blockIdx.x * 256 + t;
    int v = (i < N) ? deg[i] : 0;
    sm[t] = v;
    __syncthreads();
    for (int d = 1; d < 256; d <<= 1) {
        int add = (t >= d) ? sm[t - d] : 0;
        __syncthreads();
        sm[t] += add;
        __syncthreads();
    }
    if (i < N) part[i] = sm[t] - v;  // exclusive
    if (t == 255) bsum[blockIdx.x] = sm[255];
}

__global__ void k_scan2(int* __restrict__ bsum, int nb) {
    __shared__ int sm[512];
    int t = threadIdx.x;
    int v = (t < nb) ? bsum[t] : 0;
    sm[t] = v;
    __syncthreads();
    for (int d = 1; d < 512; d <<= 1) {
        int add = (t >= d) ? sm[t - d] : 0;
        __syncthreads();
        sm[t] += add;
        __syncthreads();
    }
    if (t < nb) bsum[t] = sm[t] - v;  // exclusive block offsets
}

__global__ void k_scan3(const int* __restrict__ part, const int* __restrict__ bsum,
                        int* __restrict__ off, int* __restrict__ cursor, int N, int E) {
    int i = blockIdx.x * 256 + threadIdx.x;
    if (i < N) {
        int o = part[i] + bsum[blockIdx.x];
        off[i] = o;
        cursor[i] = o;
    }
    if (i == 0) off[N] = E;
}

// XCD-partitioned fill (blockIdx%8 ~ XCD): rowlist2 writes for node-range r
// come only from one XCD and span ~3.2MB -> lines fill in its L2 before
// writeback. Stores {row, eid} so the edge kernel can run in CSR order.
__global__ void k_fill_part(const int* __restrict__ row, const int* __restrict__ col,
                            int* __restrict__ cursor, int2* __restrict__ rowlist2,
                            int E, int N) {
    int r = blockIdx.x & 7;
    int chunk = blockIdx.x >> 3;
    int nchunks = gridDim.x >> 3;
    int lo = (int)((long long)N * r >> 3);
    int hi = (int)((long long)N * (r + 1) >> 3);
    long long c0 = (long long)E * chunk / nchunks;
    long long c1 = (long long)E * (chunk + 1) / nchunks;
    for (long long e = c0 + threadIdx.x; e < c1; e += blockDim.x) {
        int c = col[e];
        if (c >= lo && c < hi) {
            int p = atomicAdd(&cursor[c], 1);
            rowlist2[p] = make_int2(row[e], (int)e);
        }
    }
}

// ---- layer 1: g1 = dinv * (x @ W1) ---------------------------------------
__global__ void k_lin1(const float* __restrict__ x, const float* __restrict__ W1,
                       const float* __restrict__ dinv, float* __restrict__ g, int N) {
    int idx = blockIdx.x * blockDim.x + threadIdx.x;
    int n = idx >> 6, f = idx & 63;
    if (n >= N) return;
    float x0 = x[n * 3 + 0], x1 = x[n * 3 + 1], x2 = x[n * 3 + 2];
    float acc = x0 * W1[f] + x1 * W1[64 + f] + x2 * W1[128 + f];
    g[idx] = dinv[n] * acc;
}

// ---- gather-aggregate: h[n] = relu(dinv[n]*(g[n] + sum_in g[r]) + b) -----
__global__ void k_gather(const float* __restrict__ g, const int* __restrict__ off,
                         const int2* __restrict__ rowlist2, const float* __restrict__ dinv,
                         const float* __restrict__ b, float* __restrict__ h, int N) {
    int tid = threadIdx.x;
    int wave = tid >> 6, lane = tid & 63;
    int n = blockIdx.x * 4 + wave;
    if (n >= N) return;
    int s = off[n], epos = off[n + 1];
    float a0 = g[(size_t)n * 64 + lane];  // self loop
    float a1 = 0.f, a2 = 0.f, a3 = 0.f;
    int j = s;
    for (; j + 3 < epos; j += 4) {
        int r0 = rowlist2[j].x, r1 = rowlist2[j + 1].x;
        int r2 = rowlist2[j + 2].x, r3 = rowlist2[j + 3].x;
        a0 += g[(size_t)r0 * 64 + lane];
        a1 += g[(size_t)r1 * 64 + lane];
        a2 += g[(size_t)r2 * 64 + lane];
        a3 += g[(size_t)r3 * 64 + lane];
    }
    for (; j < epos; j++) a1 += g[(size_t)rowlist2[j].x * 64 + lane];
    float acc = (a0 + a1) + (a2 + a3);
    h[(size_t)n * 64 + lane] = fmaxf(fmaf(dinv[n], acc, b[lane]), 0.0f);
}

// ---- 64x64 GEMM, wave per node: g = dinv * (h @ W) -----------------------
__global__ void k_lin64(const float* __restrict__ h, const float* __restrict__ W,
                        const float* __restrict__ dinv, float* __restrict__ g, int N) {
    __shared__ float Wl[64 * 64];
    int tid = threadIdx.x;
    for (int i = tid; i < 4096; i += 256) Wl[i] = W[i];
    __syncthreads();
    int wave = tid >> 6, lane = tid & 63;
    int n = blockIdx.x * 4 + wave;
    if (n >= N) return;
    float hv = h[(size_t)n * 64 + lane];
    float acc = 0.f;
#pragma unroll
    for (int k = 0; k < 64; k++) {
        float hk = __shfl(hv, k);
        acc = fmaf(hk, Wl[k * 64 + lane], acc);
    }
    g[(size_t)n * 64 + lane] = dinv[n] * acc;
}

// ---- edge-MLP node precompute: u = h@W3a + b3 (to u), v = h@W3b IN-PLACE -
__global__ void k_lin3(float* __restrict__ h, const float* __restrict__ W3,
                       const float* __restrict__ b3, float* __restrict__ u, int N) {
    __shared__ float Wa[4096];
    __shared__ float Wb[4096];
    int tid = threadIdx.x;
    for (int i = tid; i < 4096; i += 256) {
        Wa[i] = W3[i];
        Wb[i] = W3[4096 + i];
    }
    __syncthreads();
    int wave = tid >> 6, lane = tid & 63;
    int n = blockIdx.x * 4 + wave;
    if (n >= N) return;
    float hv = h[(size_t)n * 64 + lane];  // full row read before any store
    float ua = b3[lane], va = 0.f;
#pragma unroll
    for (int k = 0; k < 64; k++) {
        float hk = __shfl(hv, k);
        ua = fmaf(hk, Wa[k * 64 + lane], ua);
        va = fmaf(hk, Wb[k * 64 + lane], va);
    }
    u[(size_t)n * 64 + lane] = ua;
    h[(size_t)n * 64 + lane] = va;  // v overwrites h2 in place (wave-local row)
}

// ---- final, CSR order: wave per dst node; v[col] loaded once per node ----
__global__ void k_edge_csr(const float4* __restrict__ u4, const float4* __restrict__ v4,
                           const int* __restrict__ off, const int2* __restrict__ rowlist2,
                           const float4* __restrict__ w44, const float* __restrict__ b4,
                           float* __restrict__ out, int N) {
    int tid = threadIdx.x;
    int wave = tid >> 6, lane = tid & 63;
    int n = blockIdx.x * 4 + wave;
    if (n >= N) return;
    int c16 = lane & 15, grp = lane >> 4;
    int s = off[n], epos = off[n + 1];
    float4 vv = v4[(size_t)n * 16 + c16];   // once per node
    float4 w = w44[c16];
    float bb = b4[0];
    for (int j0 = s; j0 < epos; j0 += 8) {
        int ja = j0 + grp, jb = j0 + 4 + grp;
        bool va_ = ja < epos, vb_ = jb < epos;
        int2 ra = va_ ? rowlist2[ja] : make_int2(0, 0);
        int2 rb = vb_ ? rowlist2[jb] : make_int2(0, 0);
        float4 a = u4[(size_t)ra.x * 16 + c16];
        float4 b = u4[(size_t)rb.x * 16 + c16];
        float sa = fmaxf(a.x + vv.x, 0.f) * w.x + fmaxf(a.y + vv.y, 0.f) * w.y +
                   fmaxf(a.z + vv.z, 0.f) * w.z + fmaxf(a.w + vv.w, 0.f) * w.w;
        float sb = fmaxf(b.x + vv.x, 0.f) * w.x + fmaxf(b.y + vv.y, 0.f) * w.y +
                   fmaxf(b.z + vv.z, 0.f) * w.z + fmaxf(b.w + vv.w, 0.f) * w.w;
        sa += __shfl_xor(sa, 1); sa += __shfl_xor(sa, 2);
        sa += __shfl_xor(sa, 4); sa += __shfl_xor(sa, 8);
        sb += __shfl_xor(sb, 1); sb += __shfl_xor(sb, 2);
        sb += __shfl_xor(sb, 4); sb += __shfl_xor(sb, 8);
        if (c16 == 0 && va_) out[ra.y] = sa + bb;
        if (c16 == 0 && vb_) out[rb.y] = sb + bb;
    }
}

extern "C" void kernel_launch(void* const* d_in, const int* in_sizes, int n_in,
                              void* d_out, int out_size, void* d_ws, size_t ws_size,
                              hipStream_t stream) {
    const float* x  = (const float*)d_in[0];
    const int*   ei = (const int*)d_in[1];
    const float* W1 = (const float*)d_in[2];
    const float* b1 = (const float*)d_in[3];
    const float* W2 = (const float*)d_in[4];
    const float* b2 = (const float*)d_in[5];
    const float* W3 = (const float*)d_in[6];
    const float* b3 = (const float*)d_in[7];
    const float* W4 = (const float*)d_in[8];
    const float* b4 = (const float*)d_in[9];
    int N = in_sizes[0] / 3;
    int E = in_sizes[1] / 2;
    const int* row = ei;
    const int* col = ei + E;
    float* out = (float*)d_out;

    char* ws = (char*)d_ws;
    size_t off_b = 0;
    auto alloc = [&](size_t bytes) {
        void* p = ws + off_b;
        off_b += (bytes + 255) & ~(size_t)255;
        return p;
    };
    float* dinv   = (float*)alloc((size_t)N * 4);
    int*   offs   = (int*)alloc((size_t)(N + 1) * 4);
    int*   bsum   = (int*)alloc(512 * 4);
    float* bufA   = (float*)alloc((size_t)N * 64 * 4);
    float* bufB   = (float*)alloc((size_t)N * 64 * 4);
    int2*  rowlist2 = (int2*)alloc((size_t)E * 8);
    // aliases into bufA (all dead before k_lin1 writes bufA):
    int* part   = (int*)bufA;
    int* deg    = (int*)bufA + N;
    int* cursor = (int*)bufA + 2 * N;

    dim3 B(256);
    int nbN     = (N + 255) / 256;
    int nbNF    = (N * 64 + 255) / 256;
    int nbE     = (E + 255) / 256;
    int nbNode4 = (N + 3) / 4;

    // --- CSR build + normalization ---
    k_zero_i<<<nbN, B, 0, stream>>>(deg, N);
    k_hist<<<nbE, B, 0, stream>>>(col, deg, E);
    k_scan1<<<nbN, B, 0, stream>>>(deg, part, bsum, N);
    k_scan2<<<1, 512, 0, stream>>>(bsum, nbN);
    k_dinv<<<nbN, B, 0, stream>>>(deg, dinv, N);
    k_scan3<<<nbN, B, 0, stream>>>(part, bsum, offs, cursor, N, E);
    k_fill_part<<<2048, B, 0, stream>>>(row, col, cursor, rowlist2, E, N);

    // --- layer 1: g1=bufA -> h1=bufB ---
    k_lin1<<<nbNF, B, 0, stream>>>(x, W1, dinv, bufA, N);
    k_gather<<<nbNode4, B, 0, stream>>>(bufA, offs, rowlist2, dinv, b1, bufB, N);
    // --- layer 2: g2=bufA -> h2=bufB ---
    k_lin64<<<nbNode4, B, 0, stream>>>(bufB, W2, dinv, bufA, N);
    k_gather<<<nbNode4, B, 0, stream>>>(bufA, offs, rowlist2, dinv, b2, bufB, N);
    // --- edge MLP: u=bufA, v=bufB (in place over h2) ---
    k_lin3<<<nbNode4, B, 0, stream>>>(bufB, W3, b3, bufA, N);
    k_edge_csr<<<nbNode4, B, 0, stream>>>((const float4*)bufA, (const float4*)bufB,
                                          offs, rowlist2, (const float4*)W4, b4, out, N);
}

// Round 5
// 802.649 us; speedup vs baseline: 7.5387x; 1.1287x over previous
//
#include <hip/hip_runtime.h>

// ---- CSR build -----------------------------------------------------------
__global__ void k_zero_i(int* __restrict__ p, int N) {
    int i = blockIdx.x * blockDim.x + threadIdx.x;
    if (i < N) p[i] = 0;
}

__global__ void k_hist(const int* __restrict__ col, int* __restrict__ deg, int E) {
    int e = blockIdx.x * blockDim.x + threadIdx.x;
    if (e < E) atomicAdd(&deg[__builtin_nontemporal_load(&col[e])], 1);
}

// dinv = rsqrt(deg+1); y4 = {dinv*x0, dinv*x1, dinv*x2, 0}  (layer-1 pre-agg)
__global__ void k_dinv_y(const int* __restrict__ deg, const float* __restrict__ x,
                         float* __restrict__ dinv, float4* __restrict__ y4, int N) {
    int i = blockIdx.x * blockDim.x + threadIdx.x;
    if (i >= N) return;
    float d = rsqrtf((float)deg[i] + 1.0f);
    dinv[i] = d;
    y4[i] = make_float4(d * x[i * 3 + 0], d * x[i * 3 + 1], d * x[i * 3 + 2], 0.f);
}

// block-level exclusive scan (256 elems / block)
__global__ void k_scan1(const int* __restrict__ deg, int* __restrict__ part,
                        int* __restrict__ bsum, int N) {
    __shared__ int sm[256];
    int t = threadIdx.x;
    int i = blockIdx.x * 256 + t;
    int v = (i < N) ? deg[i] : 0;
    sm[t] = v;
    __syncthreads();
    for (int d = 1; d < 256; d <<= 1) {
        int add = (t >= d) ? sm[t - d] : 0;
        __syncthreads();
        sm[t] += add;
        __syncthreads();
    }
    if (i < N) part[i] = sm[t] - v;  // exclusive
    if (t == 255) bsum[blockIdx.x] = sm[255];
}

__global__ void k_scan2(int* __restrict__ bsum, int nb) {
    __shared__ int sm[512];
    int t = threadIdx.x;
    int v = (t < nb) ? bsum[t] : 0;
    sm[t] = v;
    __syncthreads();
    for (int d = 1; d < 512; d <<= 1) {
        int add = (t >= d) ? sm[t - d] : 0;
        __syncthreads();
        sm[t] += add;
        __syncthreads();
    }
    if (t < nb) bsum[t] = sm[t] - v;  // exclusive block offsets
}

__global__ void k_scan3(const int* __restrict__ part, const int* __restrict__ bsum,
                        int* __restrict__ off, int* __restrict__ cursor, int N, int E) {
    int i = blockIdx.x * 256 + threadIdx.x;
    if (i < N) {
        int o = part[i] + bsum[blockIdx.x];
        off[i] = o;
        cursor[i] = o;
    }
    if (i == 0) off[N] = E;
}

// XCD-partitioned fill (blockIdx%8 ~ XCD) + NON-TEMPORAL streaming reads so
// the col/row streams don't evict partially-filled rowlist2 lines from L2.
__global__ void k_fill_part(const int* __restrict__ row, const int* __restrict__ col,
                            int* __restrict__ cursor, int2* __restrict__ rowlist2,
                            int E, int N) {
    int r = blockIdx.x & 7;
    int chunk = blockIdx.x >> 3;
    int nchunks = gridDim.x >> 3;
    int lo = (int)((long long)N * r >> 3);
    int hi = (int)((long long)N * (r + 1) >> 3);
    long long c0 = (long long)E * chunk / nchunks;
    long long c1 = (long long)E * (chunk + 1) / nchunks;
    for (long long e = c0 + threadIdx.x; e < c1; e += blockDim.x) {
        int c = __builtin_nontemporal_load(&col[e]);
        if (c >= lo && c < hi) {
            int rr = __builtin_nontemporal_load(&row[e]);
            int p = atomicAdd(&cursor[c], 1);
            rowlist2[p] = make_int2(rr, (int)e);
        }
    }
}

// ---- fused layer1+lin2: agg3 = y[n]+sum y[r]; h1 = relu(dinv*(agg3@W1)+b1);
//      g2 = dinv * (h1 @ W2). h1 never materialized. ------------------------
__global__ void k_layer12(const float4* __restrict__ y4, const int* __restrict__ off,
                          const int2* __restrict__ rowlist2, const float* __restrict__ dinv,
                          const float* __restrict__ W1, const float* __restrict__ b1,
                          const float* __restrict__ W2, float* __restrict__ g2, int N) {
    __shared__ float W2l[4096];
    __shared__ float W1l[192];
    int tid = threadIdx.x;
    for (int i = tid; i < 4096; i += 256) W2l[i] = W2[i];
    if (tid < 192) W1l[tid] = W1[tid];
    __syncthreads();
    int wave = tid >> 6, lane = tid & 63;
    int n = blockIdx.x * 4 + wave;
    if (n >= N) return;
    int s = off[n], epos = off[n + 1];
    float ax, ay, az;
    {
        float4 self = y4[n];
        ax = (lane == 0) ? self.x : 0.f;
        ay = (lane == 0) ? self.y : 0.f;
        az = (lane == 0) ? self.z : 0.f;
    }
    for (int j = s + lane; j < epos; j += 64) {
        float4 t = y4[rowlist2[j].x];
        ax += t.x; ay += t.y; az += t.z;
    }
#pragma unroll
    for (int d = 1; d < 64; d <<= 1) {
        ax += __shfl_xor(ax, d);
        ay += __shfl_xor(ay, d);
        az += __shfl_xor(az, d);
    }
    float dn = dinv[n];
    float h1 = fmaxf(fmaf(dn, ax * W1l[lane] + ay * W1l[64 + lane] + az * W1l[128 + lane],
                          b1[lane]), 0.0f);
    float acc2 = 0.f;
#pragma unroll
    for (int k = 0; k < 64; k++) {
        float hk = __shfl(h1, k);
        acc2 = fmaf(hk, W2l[k * 64 + lane], acc2);
    }
    g2[(size_t)n * 64 + lane] = dn * acc2;
}

// ---- gather-aggregate (64-dim): h[n] = relu(dinv[n]*(g[n]+sum g[r]) + b) --
__global__ void k_gather(const float* __restrict__ g, const int* __restrict__ off,
                         const int2* __restrict__ rowlist2, const float* __restrict__ dinv,
                         const float* __restrict__ b, float* __restrict__ h, int N) {
    int tid = threadIdx.x;
    int wave = tid >> 6, lane = tid & 63;
    int n = blockIdx.x * 4 + wave;
    if (n >= N) return;
    int s = off[n], epos = off[n + 1];
    float a0 = g[(size_t)n * 64 + lane];  // self loop
    float a1 = 0.f, a2 = 0.f, a3 = 0.f;
    int j = s;
    for (; j + 3 < epos; j += 4) {
        int r0 = rowlist2[j].x, r1 = rowlist2[j + 1].x;
        int r2 = rowlist2[j + 2].x, r3 = rowlist2[j + 3].x;
        a0 += g[(size_t)r0 * 64 + lane];
        a1 += g[(size_t)r1 * 64 + lane];
        a2 += g[(size_t)r2 * 64 + lane];
        a3 += g[(size_t)r3 * 64 + lane];
    }
    for (; j < epos; j++) a1 += g[(size_t)rowlist2[j].x * 64 + lane];
    float acc = (a0 + a1) + (a2 + a3);
    h[(size_t)n * 64 + lane] = fmaxf(fmaf(dinv[n], acc, b[lane]), 0.0f);
}

// ---- edge-MLP node precompute: u = h@W3a + b3 (to u), v = h@W3b IN-PLACE -
__global__ void k_lin3(float* __restrict__ h, const float* __restrict__ W3,
                       const float* __restrict__ b3, float* __restrict__ u, int N) {
    __shared__ float Wa[4096];
    __shared__ float Wb[4096];
    int tid = threadIdx.x;
    for (int i = tid; i < 4096; i += 256) {
        Wa[i] = W3[i];
        Wb[i] = W3[4096 + i];
    }
    __syncthreads();
    int wave = tid >> 6, lane = tid & 63;
    int n = blockIdx.x * 4 + wave;
    if (n >= N) return;
    float hv = h[(size_t)n * 64 + lane];  // full row read before any store
    float ua = b3[lane], va = 0.f;
#pragma unroll
    for (int k = 0; k < 64; k++) {
        float hk = __shfl(hv, k);
        ua = fmaf(hk, Wa[k * 64 + lane], ua);
        va = fmaf(hk, Wb[k * 64 + lane], va);
    }
    u[(size_t)n * 64 + lane] = ua;
    h[(size_t)n * 64 + lane] = va;  // v overwrites h2 in place (wave-local row)
}

// ---- final, CSR order: wave per dst node; v[col] loaded once per node ----
__global__ void k_edge_csr(const float4* __restrict__ u4, const float4* __restrict__ v4,
                           const int* __restrict__ off, const int2* __restrict__ rowlist2,
                           const float4* __restrict__ w44, const float* __restrict__ b4,
                           float* __restrict__ out, int N) {
    int tid = threadIdx.x;
    int wave = tid >> 6, lane = tid & 63;
    int n = blockIdx.x * 4 + wave;
    if (n >= N) return;
    int c16 = lane & 15, grp = lane >> 4;
    int s = off[n], epos = off[n + 1];
    float4 vv = v4[(size_t)n * 16 + c16];   // once per node
    float4 w = w44[c16];
    float bb = b4[0];
    for (int j0 = s; j0 < epos; j0 += 8) {
        int ja = j0 + grp, jb = j0 + 4 + grp;
        bool va_ = ja < epos, vb_ = jb < epos;
        int2 ra = va_ ? rowlist2[ja] : make_int2(0, 0);
        int2 rb = vb_ ? rowlist2[jb] : make_int2(0, 0);
        float4 a = u4[(size_t)ra.x * 16 + c16];
        float4 b = u4[(size_t)rb.x * 16 + c16];
        float sa = fmaxf(a.x + vv.x, 0.f) * w.x + fmaxf(a.y + vv.y, 0.f) * w.y +
                   fmaxf(a.z + vv.z, 0.f) * w.z + fmaxf(a.w + vv.w, 0.f) * w.w;
        float sb = fmaxf(b.x + vv.x, 0.f) * w.x + fmaxf(b.y + vv.y, 0.f) * w.y +
                   fmaxf(b.z + vv.z, 0.f) * w.z + fmaxf(b.w + vv.w, 0.f) * w.w;
        sa += __shfl_xor(sa, 1); sa += __shfl_xor(sa, 2);
        sa += __shfl_xor(sa, 4); sa += __shfl_xor(sa, 8);
        sb += __shfl_xor(sb, 1); sb += __shfl_xor(sb, 2);
        sb += __shfl_xor(sb, 4); sb += __shfl_xor(sb, 8);
        if (c16 == 0 && va_) out[ra.y] = sa + bb;
        if (c16 == 0 && vb_) out[rb.y] = sb + bb;
    }
}

extern "C" void kernel_launch(void* const* d_in, const int* in_sizes, int n_in,
                              void* d_out, int out_size, void* d_ws, size_t ws_size,
                              hipStream_t stream) {
    const float* x  = (const float*)d_in[0];
    const int*   ei = (const int*)d_in[1];
    const float* W1 = (const float*)d_in[2];
    const float* b1 = (const float*)d_in[3];
    const float* W2 = (const float*)d_in[4];
    const float* b2 = (const float*)d_in[5];
    const float* W3 = (const float*)d_in[6];
    const float* b3 = (const float*)d_in[7];
    const float* W4 = (const float*)d_in[8];
    const float* b4 = (const float*)d_in[9];
    int N = in_sizes[0] / 3;
    int E = in_sizes[1] / 2;
    const int* row = ei;
    const int* col = ei + E;
    float* out = (float*)d_out;

    char* ws = (char*)d_ws;
    size_t off_b = 0;
    auto alloc = [&](size_t bytes) {
        void* p = ws + off_b;
        off_b += (bytes + 255) & ~(size_t)255;
        return p;
    };
    float* dinv   = (float*)alloc((size_t)N * 4);
    int*   offs   = (int*)alloc((size_t)(N + 1) * 4);
    int*   bsum   = (int*)alloc(512 * 4);
    float* bufA   = (float*)alloc((size_t)N * 64 * 4);   // g2, then u
    float* bufB   = (float*)alloc((size_t)N * 64 * 4);   // y4, then h2/v
    int2*  rowlist2 = (int2*)alloc((size_t)E * 8);
    // aliases into bufA (all dead before k_layer12 writes g2=bufA):
    int* part   = (int*)bufA;
    int* deg    = (int*)bufA + N;
    int* cursor = (int*)bufA + 2 * N;
    // y4 aliases bufB (dead before k_gather writes h2=bufB):
    float4* y4 = (float4*)bufB;

    dim3 B(256);
    int nbN     = (N + 255) / 256;
    int nbE     = (E + 255) / 256;
    int nbNode4 = (N + 3) / 4;

    // --- CSR build + normalization ---
    k_zero_i<<<nbN, B, 0, stream>>>(deg, N);
    k_hist<<<nbE, B, 0, stream>>>(col, deg, E);
    k_scan1<<<nbN, B, 0, stream>>>(deg, part, bsum, N);
    k_scan2<<<1, 512, 0, stream>>>(bsum, nbN);
    k_dinv_y<<<nbN, B, 0, stream>>>(deg, x, dinv, y4, N);
    k_scan3<<<nbN, B, 0, stream>>>(part, bsum, offs, cursor, N, E);
    k_fill_part<<<2048, B, 0, stream>>>(row, col, cursor, rowlist2, E, N);

    // --- fused layer1 + lin2: writes g2=bufA ---
    k_layer12<<<nbNode4, B, 0, stream>>>(y4, offs, rowlist2, dinv, W1, b1, W2, bufA, N);
    // --- layer 2 aggregate: h2=bufB ---
    k_gather<<<nbNode4, B, 0, stream>>>(bufA, offs, rowlist2, dinv, b2, bufB, N);
    // --- edge MLP precompute: u=bufA, v in place over h2=bufB ---
    k_lin3<<<nbNode4, B, 0, stream>>>(bufB, W3, b3, bufA, N);
    k_edge_csr<<<nbNode4, B, 0, stream>>>((const float4*)bufA, (const float4*)bufB,
                                          offs, rowlist2, (const float4*)W4, b4, out, N);
}